// Round 4
// baseline (169.650 us; speedup 1.0000x reference)
//
#include <hip/hip_runtime.h>

// S = 1024*1024, ranks [1,3,3,3,3,1].
#define SDIM (1024 * 1024)
#define GROUPS (SDIM / 4)            // float4 groups of s (262144)
#define GPT 4                        // z-float4-groups per thread in K1
#define CHUNKS (GROUPS / (256 * GPT))// 256 chunks per plane
#define NPLANE 10                    // TT0 (1 plane) + TT1..TT3 (3 planes each)
#define CHUNK_F4 (256 * GPT * 3)     // plane float4s per chunk (3072)

// K1: grid (CHUNKS, NPLANE), 256 threads. Round-4 change: COALESCED plane reads.
// Round-0 read each lane's 48B (3 x dwordx4, 48B lane stride): every 64B line is
// requested by 3 separate instructions -> 144 line-requests/wave-iter for 48
// unique lines, ~3x pressure on the per-CU L1 miss path (theory: that's why the
// demand rate plateaus at ~3.9 TB/s vs 6.3 TB/s copy). Now each iteration reads
// the block's 12KB region as 3 unit-stride float4 sweeps (each line requested
// once), z comes from a 16KB LDS stage, and the 4-vs-3 phase mismatch uses the
// round-1-verified rotated-accumulator trick (3 accs, un-rotate once at tail).
// Geometry, accumulator count, and the 18-shuffle tail match round 0 exactly.
__global__ __launch_bounds__(256) void ftt_k1(
    const float* __restrict__ z,
    const float* __restrict__ t0,
    const float* __restrict__ t1,
    const float* __restrict__ t2,
    const float* __restrict__ t3,
    float* __restrict__ partials)   // [NPLANE][CHUNKS][4]
{
    const int plane = blockIdx.y;
    const int bx = blockIdx.x;
    const int t = threadIdx.x;

    const float* base;
    if (plane == 0) {
        base = t0;
    } else {
        const int pk = plane - 1;
        const int k = pk / 3;                        // wave-uniform
        const float* tk = (k == 0) ? t1 : (k == 1) ? t2 : t3;
        base = tk + (pk % 3) * (3 * SDIM);
    }

    // ---- stage this chunk's z (4096 floats = 16KB), coalesced ----
    __shared__ __align__(16) float zl[256 * GPT * 4];
    {
        const float4* zf4 = reinterpret_cast<const float4*>(z) + bx * (256 * GPT);
        float4* zs = reinterpret_cast<float4*>(zl);
        #pragma unroll
        for (int k = 0; k < GPT; ++k) zs[t + 256 * k] = zf4[t + 256 * k];
    }
    __syncthreads();

    // ---- per-lane sweep constants (iteration-invariant) ----
    // sweep m, lane t: first flat elem e0 = 1024*m + 4*t (mod-iteration),
    // local z index d = e0/3, phase r0 = e0%3 = (m+t)%3.
    int dq[3]; bool sB[3], sC[3];
    #pragma unroll
    for (int m = 0; m < 3; ++m) {
        const int e0 = 1024 * m + 4 * t;
        dq[m] = e0 / 3;
        const int r0 = e0 % 3;
        sB[m] = (r0 <= 1);          // elem j=1 uses z0 else z1
        sC[m] = (r0 == 0);          // elem j=2 uses z0 else z1
    }

    const float4* pf = reinterpret_cast<const float4*>(base) + bx * CHUNK_F4;

    // rotated accumulators: B[k] holds q = (k + t) % 3
    float B0 = 0.f, B1 = 0.f, B2 = 0.f;

    #pragma unroll
    for (int it = 0; it < GPT; ++it) {
        const int fb = it * 768;                 // float4 base of this iteration
        const float4 v0 = pf[fb + t];            // sweep 0
        const float4 v1 = pf[fb + 256 + t];      // sweep 1
        const float4 v2 = pf[fb + 512 + t];      // sweep 2
        const int zo = 1024 * it;

        {   // sweep 0: elem j -> slot (0+j)%3 = B0,B1,B2,B0
            const float z0 = zl[dq[0] + zo], z1 = zl[dq[0] + zo + 1];
            B0 += v0.x * z0 + v0.w * z1;
            B1 += v0.y * (sB[0] ? z0 : z1);
            B2 += v0.z * (sC[0] ? z0 : z1);
        }
        {   // sweep 1: slots B1,B2,B0,B1
            const float z0 = zl[dq[1] + zo], z1 = zl[dq[1] + zo + 1];
            B1 += v1.x * z0 + v1.w * z1;
            B2 += v1.y * (sB[1] ? z0 : z1);
            B0 += v1.z * (sC[1] ? z0 : z1);
        }
        {   // sweep 2: slots B2,B0,B1,B2
            const float z0 = zl[dq[2] + zo], z1 = zl[dq[2] + zo + 1];
            B2 += v2.x * z0 + v2.w * z1;
            B0 += v2.y * (sB[2] ? z0 : z1);
            B1 += v2.z * (sC[2] ? z0 : z1);
        }
    }

    // ---- un-rotate: a[q] = B[(q - t) mod 3] ----
    const int ri = t % 3;
    float a0 = (ri == 0) ? B0 : (ri == 1) ? B2 : B1;
    float a1 = (ri == 0) ? B1 : (ri == 1) ? B0 : B2;
    float a2 = (ri == 0) ? B2 : (ri == 1) ? B1 : B0;

    // wave (64) shuffle reduction
    #pragma unroll
    for (int off = 32; off > 0; off >>= 1) {
        a0 += __shfl_down(a0, off, 64);
        a1 += __shfl_down(a1, off, 64);
        a2 += __shfl_down(a2, off, 64);
    }

    __shared__ float red[4][3];
    const int lane = t & 63;
    const int wave = t >> 6;
    if (lane == 0) { red[wave][0] = a0; red[wave][1] = a1; red[wave][2] = a2; }
    __syncthreads();
    if (t < 3) {
        const float s = red[0][t] + red[1][t] + red[2][t] + red[3][t];
        partials[(plane * CHUNKS + bx) * 4 + t] = s;
    }
}

// K2: reduce [NPLANE][CHUNKS] partial triples -> 30 sums -> f = V0@V1@V2@V3 (3 floats)
__global__ __launch_bounds__(256) void ftt_k2(
    const float* __restrict__ partials,
    float* __restrict__ fvec)
{
    __shared__ float red[NPLANE * 3][8];
    const int job = threadIdx.x >> 3;   // 0..31 (30 used): job = plane*3 + c
    const int sub = threadIdx.x & 7;    // 8 threads per job, CHUNKS/8 chunks each
    if (job < NPLANE * 3) {
        const int plane = job / 3, c = job % 3;
        float s = 0.0f;
        const int b0 = sub * (CHUNKS / 8);
        #pragma unroll 4
        for (int b = b0; b < b0 + (CHUNKS / 8); ++b)
            s += partials[(plane * CHUNKS + b) * 4 + c];
        red[job][sub] = s;
    }
    __syncthreads();

    if (threadIdx.x == 0) {
        float sum[NPLANE * 3];
        #pragma unroll
        for (int i = 0; i < NPLANE * 3; ++i) {
            float t = 0.0f;
            #pragma unroll
            for (int g = 0; g < 8; ++g) t += red[i][g];
            sum[i] = t;
        }
        float f0 = sum[0], f1 = sum[1], f2 = sum[2];
        #pragma unroll
        for (int k = 0; k < 3; ++k) {
            const float* V = &sum[3 + k * 9];   // V[r*3+q]
            const float n0 = f0 * V[0] + f1 * V[3] + f2 * V[6];
            const float n1 = f0 * V[1] + f1 * V[4] + f2 * V[7];
            const float n2 = f0 * V[2] + f1 * V[5] + f2 * V[8];
            f0 = n0; f1 = n1; f2 = n2;
        }
        fvec[0] = f0; fvec[1] = f1; fvec[2] = f2;
    }
}

// K3: out[s] = f0*TT4[0,s] + f1*TT4[1,s] + f2*TT4[2,s]   (TT4 is (3,S,1))
__global__ __launch_bounds__(256) void ftt_k3(
    const float* __restrict__ t4,
    const float* __restrict__ fvec,
    float* __restrict__ out)
{
    const int i = blockIdx.x * blockDim.x + threadIdx.x;   // float4 index
    const float f0 = fvec[0], f1 = fvec[1], f2 = fvec[2];
    const float4 a = reinterpret_cast<const float4*>(t4)[i];
    const float4 b = reinterpret_cast<const float4*>(t4 + SDIM)[i];
    const float4 c = reinterpret_cast<const float4*>(t4 + 2 * SDIM)[i];
    float4 o;
    o.x = f0 * a.x + f1 * b.x + f2 * c.x;
    o.y = f0 * a.y + f1 * b.y + f2 * c.y;
    o.z = f0 * a.z + f1 * b.z + f2 * c.z;
    o.w = f0 * a.w + f1 * b.w + f2 * c.w;
    reinterpret_cast<float4*>(out)[i] = o;
}

extern "C" void kernel_launch(void* const* d_in, const int* in_sizes, int n_in,
                              void* d_out, int out_size, void* d_ws, size_t ws_size,
                              hipStream_t stream)
{
    const float* z  = (const float*)d_in[0];
    const float* t0 = (const float*)d_in[1];
    const float* t1 = (const float*)d_in[2];
    const float* t2 = (const float*)d_in[3];
    const float* t3 = (const float*)d_in[4];
    const float* t4 = (const float*)d_in[5];
    float* out = (float*)d_out;

    float* partials = (float*)d_ws;                      // NPLANE*CHUNKS*4 floats
    float* fvec     = partials + NPLANE * CHUNKS * 4;    // 3 floats

    ftt_k1<<<dim3(CHUNKS, NPLANE), 256, 0, stream>>>(z, t0, t1, t2, t3, partials);
    ftt_k2<<<1, 256, 0, stream>>>(partials, fvec);
    ftt_k3<<<SDIM / 4 / 256, 256, 0, stream>>>(t4, fvec, out);
}